// Round 2
// baseline (4884.100 us; speedup 1.0000x reference)
//
#include <hip/hip_runtime.h>
#include <hip/hip_bf16.h>

// LSTM_66443144069713: 3-layer biLSTM, B=256 T=512 H=192 E=128, V=20000.
// fp16 MFMA input-GEMMs -> gx (chunked layout), persistent-reg recurrence
// (W_hh in VGPRs, 32 WGs x 12 waves), fp32 gate math, FC epilogue.
// Workspace-adaptive: T is split into NC chunks so gx fits ws_size.

typedef _Float16 f16;
typedef unsigned int u32;
typedef _Float16 f16x8 __attribute__((ext_vector_type(8)));
typedef float f32x4 __attribute__((ext_vector_type(4)));

__device__ __forceinline__ float sigm(float x) {
  float e = __builtin_amdgcn_exp2f(x * -1.44269504088896f);
  return __builtin_amdgcn_rcpf(1.0f + e);
}
__device__ __forceinline__ float tanh_(float x) {
  float e = __builtin_amdgcn_exp2f(x * -2.88539008177793f);
  return __builtin_fmaf(2.0f, __builtin_amdgcn_rcpf(1.0f + e), -1.0f);
}

// ---------- small utility kernels ----------

__global__ void castk(const float* __restrict__ s, f16* __restrict__ d, int n) {
  int i = blockIdx.x * 256 + threadIdx.x;
  int st = gridDim.x * 256;
  for (; i < n; i += st) d[i] = (f16)s[i];
}

// A0[t*256+b][k] = fp16(emb[x[b][t]][k])
__global__ void embedk(const int* __restrict__ x, const float* __restrict__ emb,
                       f16* __restrict__ A0) {
  int row = blockIdx.x * 8 + (threadIdx.x >> 5);
  int t = row >> 8, b = row & 255;
  int xi = x[b * 512 + t];
  int c = (threadIdx.x & 31) * 4;
  float4 v = *(const float4*)(emb + (size_t)xi * 128 + c);
  union { f16 h[4]; uint2 u; } p;
  p.h[0] = (f16)v.x; p.h[1] = (f16)v.y; p.h[2] = (f16)v.z; p.h[3] = (f16)v.w;
  *(uint2*)(A0 + (size_t)row * 128 + c) = p.u;
}

// ---------- input GEMM (one T-chunk): gx = A @ Bt^T + bias, chunked layout ----
// A rows = global (t*256+b); dir0 cols use t-window [tbf,tbf+TC), dir1 [tbb,tbb+TC).
// gx dword index: ((((dir*TC+tl)*16 + b>>4)*12 + u>>4)*512) + (g*2+qq)*64 + lane,
//   lane = ((b&15)>>2)*16 + (u&15); dword packs batch rows 2qq (lo), 2qq+1 (hi).
template <int KD>
__global__ __launch_bounds__(256, 2)
void gemmk(const f16* __restrict__ A, const f16* __restrict__ Bt,
           const float* __restrict__ bias, u32* __restrict__ gx,
           int tbf, int tbb, int TC) {
  __shared__ uint4 ldsA[1024];  // [row 128][slot 8] x 16B, slot sl holds chunk sl^(row&7)
  __shared__ uint4 ldsB[1024];
  const int tid = threadIdx.x;
  const int l = tid & 63, wid = tid >> 6;
  const int lo16 = l & 15, lhi = l >> 4;
  const int wm = wid >> 1, wn = wid & 1;
  const int dir = (blockIdx.x >= 6);
  const int c0 = blockIdx.x * 128;                      // col tile
  const int rl0 = blockIdx.y * 128;                     // local row tile
  const size_t ar0 = (size_t)(dir ? tbb : tbf) * 256 + rl0;  // global A row base

  float bj[4];
#pragma unroll
  for (int j = 0; j < 4; ++j) bj[j] = bias[c0 + wn * 64 + j * 16 + lo16];

  f32x4 acc[4][4] = {};
  constexpr int NK = KD / 64;
  uint4 ra[4], rb[4];

#define LOADK(ko_)                                                              \
  do {                                                                          \
    _Pragma("unroll") for (int i2 = 0; i2 < 4; ++i2) {                          \
      int cl = i2 * 256 + tid;                                                  \
      int row = cl >> 3, sl = cl & 7;                                           \
      int ch = sl ^ (row & 7);                                                  \
      ra[i2] = *(const uint4*)(A + (ar0 + row) * KD + (ko_)*64 + ch * 8);       \
      rb[i2] = *(const uint4*)(Bt + (size_t)(c0 + row) * KD + (ko_)*64 + ch * 8); \
    }                                                                           \
  } while (0)

  LOADK(0);
  for (int ko = 0; ko < NK; ++ko) {
    __syncthreads();
#pragma unroll
    for (int i2 = 0; i2 < 4; ++i2) {
      int cl = i2 * 256 + tid;
      int row = cl >> 3, sl = cl & 7;
      ldsA[row * 8 + sl] = ra[i2];
      ldsB[row * 8 + sl] = rb[i2];
    }
    __syncthreads();
    if (ko + 1 < NK) LOADK(ko + 1);
#pragma unroll
    for (int kk = 0; kk < 2; ++kk) {
      f16x8 af[4], bf[4];
#pragma unroll
      for (int i = 0; i < 4; ++i) {
        int rowA = wm * 64 + i * 16 + lo16;
        int slA = (kk * 4 + lhi) ^ (rowA & 7);
        af[i] = *(const f16x8*)((const char*)ldsA + rowA * 128 + slA * 16);
        int colB = wn * 64 + i * 16 + lo16;
        int slB = (kk * 4 + lhi) ^ (colB & 7);
        bf[i] = *(const f16x8*)((const char*)ldsB + colB * 128 + slB * 16);
      }
#pragma unroll
      for (int i = 0; i < 4; ++i)
#pragma unroll
        for (int j = 0; j < 4; ++j)
          acc[i][j] = __builtin_amdgcn_mfma_f32_16x16x32_f16(af[i], bf[j], acc[i][j], 0, 0, 0);
    }
  }
#undef LOADK

  // epilogue -> gx (local t within chunk)
#pragma unroll
  for (int i = 0; i < 4; ++i) {
    int rl = rl0 + wm * 64 + i * 16 + lhi * 4;  // local row; q adds 0..3 (same t,b16)
    int tl = rl >> 8;
    int b16 = (rl & 255) >> 4;
#pragma unroll
    for (int j = 0; j < 4; ++j) {
      int colb = c0 + wn * 64 + j * 16;
      int c768 = colb - dir * 768;
      int g = c768 / 192;
      int w12 = (c768 % 192) >> 4;
      size_t base = ((((size_t)dir * TC + tl) * 16 + b16) * 12 + w12) * 512;
#pragma unroll
      for (int qq = 0; qq < 2; ++qq) {
        union { f16 h[2]; u32 u; } p;
        p.h[0] = (f16)(acc[i][j][2 * qq] + bj[j]);
        p.h[1] = (f16)(acc[i][j][2 * qq + 1] + bj[j]);
        gx[base + (g * 2 + qq) * 64 + l] = p.u;
      }
    }
  }
}

// ---------- recurrence: one layer, one T-chunk, both directions ----------
// grid 32 = 2 dirs x 16 batch-blocks; 768 threads = 12 waves (wave w: units
// 16w..16w+15, all 4 gates; W_hh in VGPRs). h double-buffered LDS, 1 barrier/step.
// (h,c) carried across chunks via carh (f16) / carc (f32).
__global__ __launch_bounds__(768, 3)
void lstmk(const u32* __restrict__ gx, const float* __restrict__ Whh,
           f16* __restrict__ outh, float* __restrict__ hT,
           f16* __restrict__ carh, float* __restrict__ carc,
           int c, int NC, int TC) {
  __shared__ __align__(16) f16 hb[2][16 * 200];
  const int tid = threadIdx.x;
  const int l = tid & 63, w = tid >> 6;
  const int lo16 = l & 15, lhi = l >> 4;
  const int dir = blockIdx.x & 1, bblk = blockIdx.x >> 1;
  const int u0 = w * 16;
  const int bb = bblk * 16 + lhi * 4;
  const int dc = dir * 192;

  // W_hh B-fragments -> VGPRs (96 regs)
  f16x8 wf[4][6];
#pragma unroll
  for (int g = 0; g < 4; ++g) {
#pragma unroll
    for (int kk = 0; kk < 6; ++kk) {
      const float* s = Whh + (size_t)(dir * 768 + g * 192 + u0 + lo16) * 192 + kk * 32 + lhi * 8;
      f16x8 v;
#pragma unroll
      for (int e = 0; e < 8; ++e) v[e] = (f16)s[e];
      wf[g][kk] = v;
    }
  }

  float cq[4];
  if (c == 0) {
    f16* hz = (f16*)hb;
    for (int i = tid; i < 2 * 16 * 200; i += 768) hz[i] = (f16)0.f;
#pragma unroll
    for (int q = 0; q < 4; ++q) cq[q] = 0.f;
  } else {
#pragma unroll
    for (int q = 0; q < 4; ++q) {
      size_t ci = ((size_t)dir * 256 + bb + q) * 192 + u0 + lo16;
      cq[q] = carc[ci];
      hb[0][(lhi * 4 + q) * 200 + u0 + lo16] = carh[ci];
    }
  }
  __syncthreads();

  u32 ga[8], gb[8];
  {  // prefetch step 0 of this chunk
    const int tl0 = dir ? (TC - 1) : 0;
    size_t wb = ((((size_t)dir * TC + tl0) * 16 + bblk) * 12 + w) * 512;
#pragma unroll
    for (int k = 0; k < 8; ++k) ga[k] = gx[wb + k * 64 + l];
  }
  const int tb0 = dir ? (511 - c * TC) : (c * TC);  // global t = tb0 +/- s

#define RSTEP(S, CUR, NXT)                                                        \
  do {                                                                            \
    const int t = dir ? (tb0 - (S)) : (tb0 + (S));                                \
    {                                                                             \
      int snx = ((S) + 1 < TC) ? (S) + 1 : (S);                                   \
      int tln = dir ? (TC - 1 - snx) : snx;                                       \
      size_t wb = ((((size_t)dir * TC + tln) * 16 + bblk) * 12 + w) * 512;        \
      _Pragma("unroll") for (int k = 0; k < 8; ++k) NXT[k] = gx[wb + k * 64 + l]; \
    }                                                                             \
    f32x4 ac[4] = {};                                                             \
    {                                                                             \
      const f16* hcur = hb[(S) & 1];                                              \
      _Pragma("unroll") for (int kk = 0; kk < 6; ++kk) {                          \
        f16x8 av = *(const f16x8*)(hcur + lo16 * 200 + kk * 32 + lhi * 8);        \
        ac[0] = __builtin_amdgcn_mfma_f32_16x16x32_f16(av, wf[0][kk], ac[0], 0, 0, 0); \
        ac[1] = __builtin_amdgcn_mfma_f32_16x16x32_f16(av, wf[1][kk], ac[1], 0, 0, 0); \
        ac[2] = __builtin_amdgcn_mfma_f32_16x16x32_f16(av, wf[2][kk], ac[2], 0, 0, 0); \
        ac[3] = __builtin_amdgcn_mfma_f32_16x16x32_f16(av, wf[3][kk], ac[3], 0, 0, 0); \
      }                                                                           \
    }                                                                             \
    float z[4][4];                                                                \
    _Pragma("unroll") for (int k = 0; k < 8; ++k) {                               \
      union { u32 u; f16 h[2]; } p;                                               \
      p.u = CUR[k];                                                               \
      const int g_ = k >> 1, qq_ = k & 1;                                         \
      z[g_][2 * qq_] = ac[g_][2 * qq_] + (float)p.h[0];                           \
      z[g_][2 * qq_ + 1] = ac[g_][2 * qq_ + 1] + (float)p.h[1];                   \
    }                                                                             \
    f16* hnew = hb[((S) + 1) & 1];                                                \
    _Pragma("unroll") for (int q = 0; q < 4; ++q) {                               \
      float iv = sigm(z[0][q]), fv = sigm(z[1][q]);                               \
      float gv = tanh_(z[2][q]), ov = sigm(z[3][q]);                              \
      cq[q] = fv * cq[q] + iv * gv;                                               \
      float hv = ov * tanh_(cq[q]);                                               \
      f16 hh = (f16)hv;                                                           \
      hnew[(lhi * 4 + q) * 200 + u0 + lo16] = hh;                                 \
      outh[((size_t)t * 256 + bb + q) * 384 + dc + u0 + lo16] = hh;               \
      if ((S) == TC - 1) {                                                        \
        size_t ci = ((size_t)dir * 256 + bb + q) * 192 + u0 + lo16;               \
        carh[ci] = hh;                                                            \
        carc[ci] = cq[q];                                                         \
        if (c == NC - 1) hT[ci] = hv;                                             \
      }                                                                           \
    }                                                                             \
    asm volatile("s_waitcnt lgkmcnt(0)" ::: "memory");                            \
    __builtin_amdgcn_s_barrier();                                                 \
    asm volatile("" ::: "memory");                                                \
  } while (0)

  for (int s = 0; s < TC; s += 2) {
    RSTEP(s, ga, gb);
    RSTEP(s + 1, gb, ga);
  }
#undef RSTEP
}

__global__ void fck(const float* __restrict__ hT, const float* __restrict__ w,
                    const float* __restrict__ fb, float* __restrict__ out) {
  int b = blockIdx.x * 64 + threadIdx.x;
  float a = fb[0];
#pragma unroll 4
  for (int u = 0; u < 192; ++u)
    a += w[u] * hT[(size_t)b * 192 + u] + w[192 + u] * hT[49152 + (size_t)b * 192 + u];
  out[b] = a;
}

extern "C" void kernel_launch(void* const* d_in, const int* in_sizes, int n_in,
                              void* d_out, int out_size, void* d_ws, size_t ws_size,
                              hipStream_t stream) {
  (void)in_sizes; (void)n_in; (void)out_size;
  const int* x = (const int*)d_in[0];
  const float* emb = (const float*)d_in[1];
  const float* Wih0 = (const float*)d_in[2];
  const float* Whh0 = (const float*)d_in[3];
  const float* b0 = (const float*)d_in[4];
  const float* Wihr = (const float*)d_in[5];
  const float* Whhr = (const float*)d_in[6];
  const float* br = (const float*)d_in[7];
  const float* fcw = (const float*)d_in[8];
  const float* fcb = (const float*)d_in[9];
  float* out = (float*)d_out;

  const size_t gxFull = 402653184ull;  // [2][512][256][768] f16
  const size_t hB = 100663296ull;      // [512][256][384] f16
  const size_t smallB = 3735552ull;

  int NC = 32;
  {
    const int cands[6] = {1, 2, 4, 8, 16, 32};
    for (int i = 0; i < 6; ++i) {
      int nc = cands[i];
      size_t need = gxFull / nc + hB * (nc == 1 ? 1 : 2) + smallB;
      if (need <= ws_size) { NC = nc; break; }
    }
  }
  const int TC = 512 / NC;

  char* ws = (char*)d_ws;
  u32* gx = (u32*)ws;
  size_t off = gxFull / NC;
  f16* h0 = (f16*)(ws + off);
  f16* h1 = (NC == 1) ? h0 : (f16*)(ws + off + hB);
  off += hB * (NC == 1 ? 1 : 2);
  f16* A0 = h1;  // alias: A0 dead before h1's (or single-h's) first write
  f16* Bt0 = (f16*)(ws + off);  off += 393216ull;   // [1536][128] f16
  f16* Bt12 = (f16*)(ws + off); off += 2359296ull;  // [2][1536][384] f16
  float* hT = (float*)(ws + off); off += 393216ull; // [2][256][192] f32
  f16* carh = (f16*)(ws + off); off += 196608ull;   // [2][256][192] f16
  float* carc = (float*)(ws + off); off += 393216ull;

  castk<<<192, 256, 0, stream>>>(Wih0, Bt0, 196608);
  castk<<<1152, 256, 0, stream>>>(Wihr, Bt12, 1179648);
  embedk<<<16384, 256, 0, stream>>>(x, emb, A0);

  for (int layer = 0; layer < 3; ++layer) {
    const f16* in = (layer == 0) ? A0 : (layer == 1 ? h0 : h1);
    f16* outp = (layer == 1) ? h1 : h0;
    const float* Whh = (layer == 0) ? Whh0 : (Whhr + (layer - 1) * 294912);
    for (int cch = 0; cch < NC; ++cch) {
      int tbf = cch * TC, tbb = 512 - (cch + 1) * TC;
      if (layer == 0)
        gemmk<128><<<dim3(12, 2 * TC), 256, 0, stream>>>(in, Bt0, b0, gx, tbf, tbb, TC);
      else
        gemmk<384><<<dim3(12, 2 * TC), 256, 0, stream>>>(
            in, Bt12 + (size_t)(layer - 1) * 589824, br + (layer - 1) * 1536, gx, tbf, tbb, TC);
      lstmk<<<32, 768, 0, stream>>>(gx, Whh, outp, hT, carh, carc, cch, NC, TC);
    }
  }

  fck<<<4, 64, 0, stream>>>(hT, fcw, fcb, out);
}

// Round 3
// 3093.371 us; speedup vs baseline: 1.5789x; 1.5789x over previous
//
#include <hip/hip_runtime.h>
#include <hip/hip_bf16.h>

// LSTM_66443144069713: 3-layer biLSTM, B=256 T=512 H=192 E=128, V=20000.
// Fused pipeline: per chunk, WGs 0-31 run the recurrence for chunk c while
// WGs 32-255 compute the input-GEMM gx for chunk c+1 (ping-pong gx buffers).
// W_hh pre-cast to f16 in fragment layout (coalesced L2 loads). fp32 gate math.

typedef _Float16 f16;
typedef unsigned int u32;
typedef _Float16 f16x8 __attribute__((ext_vector_type(8)));
typedef float f32x4 __attribute__((ext_vector_type(4)));

__device__ __forceinline__ float sigm(float x) {
  float e = __builtin_amdgcn_exp2f(x * -1.44269504088896f);
  return __builtin_amdgcn_rcpf(1.0f + e);
}
__device__ __forceinline__ float tanh_(float x) {
  float e = __builtin_amdgcn_exp2f(x * -2.88539008177793f);
  return __builtin_fmaf(2.0f, __builtin_amdgcn_rcpf(1.0f + e), -1.0f);
}

// ---------- small utility kernels ----------

__global__ void castk(const float* __restrict__ s, f16* __restrict__ d, int n) {
  int i = blockIdx.x * 256 + threadIdx.x;
  int st = gridDim.x * 256;
  for (; i < n; i += st) d[i] = (f16)s[i];
}

// W_hh (f32 [2][768][192]) -> f16 fragment layout [dir][w12][g][kk][lane][8]
__global__ void castwhh(const float* __restrict__ src, f16* __restrict__ dst) {
  int o = blockIdx.x * 256 + threadIdx.x;  // < 294912
  int e = o & 7, rest = o >> 3;
  int l = rest & 63; rest >>= 6;
  int kk = rest % 6; rest /= 6;
  int g = rest & 3; rest >>= 2;
  int w = rest % 12; int dir = rest / 12;
  int lo16 = l & 15, lhi = l >> 4;
  dst[o] = (f16)src[(size_t)(dir * 768 + g * 192 + w * 16 + lo16) * 192 + kk * 32 + lhi * 8 + e];
}

// A0[t*256+b][k] = fp16(emb[x[b][t]][k])
__global__ void embedk(const int* __restrict__ x, const float* __restrict__ emb,
                       f16* __restrict__ A0) {
  int row = blockIdx.x * 8 + (threadIdx.x >> 5);
  int t = row >> 8, b = row & 255;
  int xi = x[b * 512 + t];
  int c = (threadIdx.x & 31) * 4;
  float4 v = *(const float4*)(emb + (size_t)xi * 128 + c);
  union { f16 h[4]; uint2 u; } p;
  p.h[0] = (f16)v.x; p.h[1] = (f16)v.y; p.h[2] = (f16)v.z; p.h[3] = (f16)v.w;
  *(uint2*)(A0 + (size_t)row * 128 + c) = p.u;
}

// ---------- fused kernel ----------
// gx dword index: ((((dir*TC+tl)*16 + b16)*12 + w12)*512) + (g*2+qq)*64 + lane,
//   lane = ((b&15)>>2)*16 + (u&15); dword packs batch rows 2qq (lo), 2qq+1 (hi).
template <int KD>
__global__ __launch_bounds__(768)
void fusedk(const f16* __restrict__ in, const f16* __restrict__ Bt,
            const float* __restrict__ bias,
            const u32* __restrict__ gxR, u32* __restrict__ gxW,
            const f16* __restrict__ whh16,
            f16* __restrict__ outh, float* __restrict__ hT,
            f16* __restrict__ carh, float* __restrict__ carc,
            int c, int cg, int NC, int TC, int doLstm, int wOut, int wHT) {
  union SMem {
    struct { uint4 A[1024]; uint4 B[1536]; } g;   // 16KB + 24KB
    f16 hb[2][16 * 200];                          // 12.8KB
  };
  __shared__ __align__(16) SMem sm;
  const int wg = blockIdx.x;
  const int tid = threadIdx.x;
  const int l = tid & 63, w = tid >> 6;
  const int lo16 = l & 15, lhi = l >> 4;

  if (doLstm && wg < 32) {
    // ================= recurrence part (chunk c) =================
    const int dir = wg & 1, bblk = wg >> 1;
    const int u0 = w * 16;
    const int bb = bblk * 16 + lhi * 4;
    const int dc = dir * 192;

    f16x8 wf[4][6];
#pragma unroll
    for (int g = 0; g < 4; ++g)
#pragma unroll
      for (int kk = 0; kk < 6; ++kk)
        wf[g][kk] = *(const f16x8*)(whh16 + ((((size_t)dir * 12 + w) * 4 + g) * 6 + kk) * 512 + l * 8);

    float cq[4];
    if (c == 0) {
      f16* hz = (f16*)sm.hb;
      for (int i = tid; i < 2 * 16 * 200; i += 768) hz[i] = (f16)0.f;
#pragma unroll
      for (int q = 0; q < 4; ++q) cq[q] = 0.f;
    } else {
#pragma unroll
      for (int q = 0; q < 4; ++q) {
        size_t ci = ((size_t)dir * 256 + bb + q) * 192 + u0 + lo16;
        cq[q] = carc[ci];
        sm.hb[0][(lhi * 4 + q) * 200 + u0 + lo16] = carh[ci];
      }
    }
    __syncthreads();

    u32 ga[8], gb[8];
    {
      const int tl0 = dir ? (TC - 1) : 0;
      size_t wb = ((((size_t)dir * TC + tl0) * 16 + bblk) * 12 + w) * 512;
#pragma unroll
      for (int k = 0; k < 8; ++k) ga[k] = gxR[wb + k * 64 + l];
    }
    const int tb0 = dir ? (511 - c * TC) : (c * TC);

#define RSTEP(S, CUR, NXT)                                                         \
  do {                                                                             \
    const int t = dir ? (tb0 - (S)) : (tb0 + (S));                                 \
    {                                                                              \
      int snx = ((S) + 1 < TC) ? (S) + 1 : (S);                                    \
      int tln = dir ? (TC - 1 - snx) : snx;                                        \
      size_t wb = ((((size_t)dir * TC + tln) * 16 + bblk) * 12 + w) * 512;         \
      _Pragma("unroll") for (int k = 0; k < 8; ++k) NXT[k] = gxR[wb + k * 64 + l]; \
    }                                                                              \
    f32x4 ac[4] = {};                                                              \
    {                                                                              \
      const f16* hcur = sm.hb[(S) & 1];                                            \
      _Pragma("unroll") for (int kk = 0; kk < 6; ++kk) {                           \
        f16x8 av = *(const f16x8*)(hcur + lo16 * 200 + kk * 32 + lhi * 8);         \
        ac[0] = __builtin_amdgcn_mfma_f32_16x16x32_f16(av, wf[0][kk], ac[0], 0, 0, 0); \
        ac[1] = __builtin_amdgcn_mfma_f32_16x16x32_f16(av, wf[1][kk], ac[1], 0, 0, 0); \
        ac[2] = __builtin_amdgcn_mfma_f32_16x16x32_f16(av, wf[2][kk], ac[2], 0, 0, 0); \
        ac[3] = __builtin_amdgcn_mfma_f32_16x16x32_f16(av, wf[3][kk], ac[3], 0, 0, 0); \
      }                                                                            \
    }                                                                              \
    float z[4][4];                                                                 \
    _Pragma("unroll") for (int k = 0; k < 8; ++k) {                                \
      union { u32 u; f16 h[2]; } p;                                                \
      p.u = CUR[k];                                                                \
      const int g_ = k >> 1, qq_ = k & 1;                                          \
      z[g_][2 * qq_] = ac[g_][2 * qq_] + (float)p.h[0];                            \
      z[g_][2 * qq_ + 1] = ac[g_][2 * qq_ + 1] + (float)p.h[1];                    \
    }                                                                              \
    f16* hnew = sm.hb[((S) + 1) & 1];                                              \
    _Pragma("unroll") for (int q = 0; q < 4; ++q) {                                \
      float iv = sigm(z[0][q]), fv = sigm(z[1][q]);                                \
      float gv = tanh_(z[2][q]), ov = sigm(z[3][q]);                               \
      cq[q] = fv * cq[q] + iv * gv;                                                \
      float hv = ov * tanh_(cq[q]);                                                \
      f16 hh = (f16)hv;                                                            \
      hnew[(lhi * 4 + q) * 200 + u0 + lo16] = hh;                                  \
      if (wOut) outh[((size_t)t * 256 + bb + q) * 384 + dc + u0 + lo16] = hh;      \
      if ((S) == TC - 1) {                                                         \
        size_t ci = ((size_t)dir * 256 + bb + q) * 192 + u0 + lo16;                \
        carh[ci] = hh;                                                             \
        carc[ci] = cq[q];                                                          \
        if (wHT && c == NC - 1) hT[ci] = hv;                                       \
      }                                                                            \
    }                                                                              \
    asm volatile("s_waitcnt lgkmcnt(0)" ::: "memory");                             \
    __builtin_amdgcn_s_barrier();                                                  \
    asm volatile("" ::: "memory");                                                 \
  } while (0)

    for (int s = 0; s < TC; s += 2) {
      RSTEP(s, ga, gb);
      RSTEP(s + 1, gb, ga);
    }
#undef RSTEP
    return;
  }

  // ================= GEMM part (chunk cg -> gxW) =================
  if (cg >= NC) return;
  const int pool = doLstm ? 224 : 256;
  const int gid = doLstm ? wg - 32 : wg;
  const int RT = TC * 2;          // 128-row tiles per direction
  const int ntiles = RT * 8;      // 2 dirs * RT * 4 gates
  const int tbf = cg * TC, tbb = 512 - (cg + 1) * TC;
  const int wm = (w >> 1) & 1;    // hmm: 12 waves -> wm in {0,1}, wn in {0..5}
  const int wmm = w / 6, wn = w % 6;
  (void)wm;
  constexpr int NKc = KD / 64;

  for (int tt = gid; tt < ntiles; tt += pool) {
    const int g = tt & 3;
    const int r = (tt >> 2) % RT;
    const int dir = (tt >> 2) / RT;
    const size_t ar0 = (size_t)(dir ? tbb : tbf) * 256 + r * 128;  // A row base
    const int btr0 = dir * 768 + g * 192;                          // Bt row base

    float bj[2];
#pragma unroll
    for (int j = 0; j < 2; ++j) bj[j] = bias[btr0 + wn * 32 + j * 16 + lo16];

    f32x4 acc[4][2] = {};
    uint4 a0, a1, b0, b1;

#define LDG(ko_)                                                                   \
  do {                                                                             \
    { int idx = tid; int row = idx >> 3, sl = idx & 7; int ch = sl ^ (row & 7);    \
      a0 = *(const uint4*)(in + (ar0 + row) * KD + (ko_)*64 + ch * 8); }           \
    if (tid < 256) { int idx = tid + 768; int row = idx >> 3, sl = idx & 7;        \
      int ch = sl ^ (row & 7);                                                     \
      a1 = *(const uint4*)(in + (ar0 + row) * KD + (ko_)*64 + ch * 8); }           \
    { int idx = tid; int row = idx >> 3, sl = idx & 7; int ch = sl ^ (row & 7);    \
      b0 = *(const uint4*)(Bt + (size_t)(btr0 + row) * KD + (ko_)*64 + ch * 8); }  \
    { int idx = tid + 768; int row = idx >> 3, sl = idx & 7; int ch = sl ^ (row & 7); \
      b1 = *(const uint4*)(Bt + (size_t)(btr0 + row) * KD + (ko_)*64 + ch * 8); }  \
  } while (0)

    LDG(0);
    for (int ko = 0; ko < NKc; ++ko) {
      __syncthreads();
      sm.g.A[tid] = a0;
      if (tid < 256) sm.g.A[tid + 768] = a1;
      sm.g.B[tid] = b0;
      sm.g.B[tid + 768] = b1;
      __syncthreads();
      if (ko + 1 < NKc) LDG(ko + 1);
#pragma unroll
      for (int kk = 0; kk < 2; ++kk) {
        f16x8 af[4], bf[2];
#pragma unroll
        for (int i = 0; i < 4; ++i) {
          int rowA = wmm * 64 + i * 16 + lo16;
          int slA = (kk * 4 + lhi) ^ (rowA & 7);
          af[i] = *(const f16x8*)((const char*)sm.g.A + rowA * 128 + slA * 16);
        }
#pragma unroll
        for (int j = 0; j < 2; ++j) {
          int colB = wn * 32 + j * 16 + lo16;
          int slB = (kk * 4 + lhi) ^ (colB & 7);
          bf[j] = *(const f16x8*)((const char*)sm.g.B + colB * 128 + slB * 16);
        }
#pragma unroll
        for (int i = 0; i < 4; ++i)
#pragma unroll
          for (int j = 0; j < 2; ++j)
            acc[i][j] = __builtin_amdgcn_mfma_f32_16x16x32_f16(af[i], bf[j], acc[i][j], 0, 0, 0);
      }
    }
#undef LDG

    // epilogue -> gxW
#pragma unroll
    for (int i = 0; i < 4; ++i) {
      int rl = r * 128 + wmm * 64 + i * 16 + lhi * 4;  // local row; q adds 0..3
      int tl = rl >> 8;
      int b16 = (rl & 255) >> 4;
#pragma unroll
      for (int j = 0; j < 2; ++j) {
        int w12 = wn * 2 + j;
        size_t base = ((((size_t)dir * TC + tl) * 16 + b16) * 12 + w12) * 512;
#pragma unroll
        for (int qq = 0; qq < 2; ++qq) {
          union { f16 h[2]; u32 u; } p;
          p.h[0] = (f16)(acc[i][j][2 * qq] + bj[j]);
          p.h[1] = (f16)(acc[i][j][2 * qq + 1] + bj[j]);
          gxW[base + (g * 2 + qq) * 64 + l] = p.u;
        }
      }
    }
    __syncthreads();  // protect LDS reuse across tile loop
  }
}

__global__ void fck(const float* __restrict__ hT, const float* __restrict__ w,
                    const float* __restrict__ fb, float* __restrict__ out) {
  int b = blockIdx.x * 64 + threadIdx.x;
  float a = fb[0];
#pragma unroll 4
  for (int u = 0; u < 192; ++u)
    a += w[u] * hT[(size_t)b * 192 + u] + w[192 + u] * hT[49152 + (size_t)b * 192 + u];
  out[b] = a;
}

extern "C" void kernel_launch(void* const* d_in, const int* in_sizes, int n_in,
                              void* d_out, int out_size, void* d_ws, size_t ws_size,
                              hipStream_t stream) {
  (void)in_sizes; (void)n_in; (void)out_size;
  const int* x = (const int*)d_in[0];
  const float* emb = (const float*)d_in[1];
  const float* Wih0 = (const float*)d_in[2];
  const float* Whh0 = (const float*)d_in[3];
  const float* b0 = (const float*)d_in[4];
  const float* Wihr = (const float*)d_in[5];
  const float* Whhr = (const float*)d_in[6];
  const float* br = (const float*)d_in[7];
  const float* fcw = (const float*)d_in[8];
  const float* fcb = (const float*)d_in[9];
  float* out = (float*)d_out;

  const size_t gxFull = 402653184ull;  // [2][512][256][768] f16
  const size_t hB = 100663296ull;      // [512][256][384] f16
  const size_t fixed = 2 * hB + 1179648 + 589824 + 393216 + 196608 + 393216;

  int NC;
  if (fixed + 2 * (gxFull / 32) <= ws_size) NC = 32;
  else if (fixed + 2 * (gxFull / 64) <= ws_size) NC = 64;
  else NC = 128;
  const int TC = 512 / NC;
  const size_t chunkB = gxFull / NC;

  char* ws = (char*)d_ws;
  u32* gxb[2] = {(u32*)ws, (u32*)(ws + chunkB)};
  size_t off = 2 * chunkB;
  f16* h0 = (f16*)(ws + off); off += hB;
  f16* h1 = (f16*)(ws + off); off += hB;
  f16* A0 = h1;  // alias: A0 dead before h1's first write (layer-1 lstm)
  f16* Bt = (f16*)(ws + off); off += 1179648ull;     // [1536][384] f16 (per-layer)
  f16* whh16 = (f16*)(ws + off); off += 589824ull;   // fragment layout (per-layer)
  float* hT = (float*)(ws + off); off += 393216ull;  // [2][256][192] f32
  f16* carh = (f16*)(ws + off); off += 196608ull;
  float* carc = (float*)(ws + off); off += 393216ull;

  embedk<<<16384, 256, 0, stream>>>(x, emb, A0);

  for (int layer = 0; layer < 3; ++layer) {
    const f16* in = (layer == 0) ? A0 : (layer == 1 ? h0 : h1);
    f16* outp = (layer == 1) ? h1 : h0;  // layer 2: unused (wOut=0)
    const int wOut = (layer < 2) ? 1 : 0;
    const int wHT = (layer == 2) ? 1 : 0;
    const float* bias = (layer == 0) ? b0 : (br + (layer - 1) * 1536);

    if (layer == 0) {
      castk<<<192, 256, 0, stream>>>(Wih0, Bt, 196608);
      castwhh<<<1152, 256, 0, stream>>>(Whh0, whh16);
    } else {
      castk<<<1152, 256, 0, stream>>>(Wihr + (size_t)(layer - 1) * 589824, Bt, 589824);
      castwhh<<<1152, 256, 0, stream>>>(Whhr + (size_t)(layer - 1) * 294912, whh16);
    }

    // prologue: gemm chunk 0 with all 256 WGs
    if (layer == 0)
      fusedk<128><<<256, 768, 0, stream>>>(in, Bt, bias, gxb[0], gxb[0], whh16,
                                           outp, hT, carh, carc, 0, 0, NC, TC, 0, wOut, wHT);
    else
      fusedk<384><<<256, 768, 0, stream>>>(in, Bt, bias, gxb[0], gxb[0], whh16,
                                           outp, hT, carh, carc, 0, 0, NC, TC, 0, wOut, wHT);

    for (int c = 0; c < NC; ++c) {
      const u32* gR = gxb[c & 1];
      u32* gW = gxb[(c + 1) & 1];
      if (layer == 0)
        fusedk<128><<<256, 768, 0, stream>>>(in, Bt, bias, gR, gW, whh16,
                                             outp, hT, carh, carc, c, c + 1, NC, TC, 1, wOut, wHT);
      else
        fusedk<384><<<256, 768, 0, stream>>>(in, Bt, bias, gR, gW, whh16,
                                             outp, hT, carh, carc, c, c + 1, NC, TC, 1, wOut, wHT);
    }
  }

  fck<<<4, 64, 0, stream>>>(hT, fcw, fcb, out);
}